// Round 5
// baseline (387.158 us; speedup 1.0000x reference)
//
#include <hip/hip_runtime.h>
#include <hip/hip_bf16.h>
#include <math.h>

#define T_TOK 4096
#define H_DIM 2048
#define NH 16
#define NKV 8
#define HD 128
#define QS (NH * HD)        // 2048
#define KVS (NKV * HD)      // 1024
#define QKV_W (QS + 2*KVS)  // 4096
// SCALE * log2(e): Q pre-scaled so softmax runs in exp2 domain
#define QSCALE (0.08838834764831845f * 1.4426950408889634f)
#define EPS 1e-6f

typedef short short8 __attribute__((ext_vector_type(8)));
typedef short short4v __attribute__((ext_vector_type(4)));
typedef float floatx4 __attribute__((ext_vector_type(4)));

#if __has_builtin(__builtin_amdgcn_exp2f)
#define EXP2(x) __builtin_amdgcn_exp2f(x)
#else
#define EXP2(x) exp2f(x)
#endif

__device__ __forceinline__ unsigned short f2bf(float f) {
    unsigned int u = __float_as_uint(f);
    unsigned int r = (u + 0x7FFFu + ((u >> 16) & 1u)) >> 16;   // RNE
    return (unsigned short)r;
}
__device__ __forceinline__ float bf2f(unsigned short u) {
    unsigned int v = ((unsigned int)u) << 16;
    return __uint_as_float(v);
}
// packed f32x2 -> bf16x2
__device__ __forceinline__ unsigned int pk2(float a, float b) {
    union { __hip_bfloat162 h; unsigned int u; } c;
    c.h = __float22bfloat162_rn(make_float2(a, b));
    return c.u;
}

// async global->LDS 16B: LDS dest is wave-uniform base + lane*16
__device__ __forceinline__ void gload_lds16(const unsigned short* g, unsigned short* l) {
    __builtin_amdgcn_global_load_lds(
        (const __attribute__((address_space(1))) unsigned int*)(const void*)g,
        (__attribute__((address_space(3))) unsigned int*)(void*)l, 16, 0, 0);
}

// ---------------- f32 -> bf16 flat convert ---------------------------------
__global__ __launch_bounds__(256) void cvt_bf16(const float* __restrict__ in,
                                                unsigned short* __restrict__ out) {
    int idx = (blockIdx.x * 256 + threadIdx.x) * 8;
    float4 v0 = *(const float4*)&in[idx];
    float4 v1 = *(const float4*)&in[idx + 4];
    short8 t;
    t[0] = (short)f2bf(v0.x); t[1] = (short)f2bf(v0.y);
    t[2] = (short)f2bf(v0.z); t[3] = (short)f2bf(v0.w);
    t[4] = (short)f2bf(v1.x); t[5] = (short)f2bf(v1.y);
    t[6] = (short)f2bf(v1.z); t[7] = (short)f2bf(v1.w);
    *(short8*)&out[idx] = t;
}

// ------------- f32 [K][N] -> bf16 [N][K] transpose+convert -----------------
__global__ __launch_bounds__(256) void cvt_transpose(const float* __restrict__ in,
                                                     unsigned short* __restrict__ out,
                                                     int K, int N) {
    __shared__ __align__(16) unsigned short t[64][72];
    const int tid = threadIdx.x;
    const int n0 = blockIdx.x * 64, k0 = blockIdx.y * 64;
    const int r = tid >> 4, c4 = (tid & 15) * 4;
    #pragma unroll
    for (int i = 0; i < 4; ++i) {
        int kk = r + 16 * i;
        float4 v = *(const float4*)&in[(size_t)(k0 + kk) * N + n0 + c4];
        t[c4 + 0][kk] = f2bf(v.x); t[c4 + 1][kk] = f2bf(v.y);
        t[c4 + 2][kk] = f2bf(v.z); t[c4 + 3][kk] = f2bf(v.w);
    }
    __syncthreads();
    const int n = tid >> 2, c8 = (tid & 3) * 16;
    short8 a = *(const short8*)&t[n][c8];
    short8 b = *(const short8*)&t[n][c8 + 8];
    *(short8*)&out[(size_t)(n0 + n) * K + k0 + c8] = a;
    *(short8*)&out[(size_t)(n0 + n) * K + k0 + c8 + 8] = b;
}

// ====== m97-style bf16 GEMM: C[M,N] = A[M,K] @ Bt[N,K]^T, global_load_lds ==
template<bool C_BF16>
__global__ __launch_bounds__(256) void gemm_bt(const unsigned short* __restrict__ A, int lda,
                                               const unsigned short* __restrict__ Bt, int ldb,
                                               void* __restrict__ Cptr, int ldc, int K) {
    __shared__ __align__(16) unsigned short As[128 * 32];
    __shared__ __align__(16) unsigned short Bs[128 * 32];
    const int tid = threadIdx.x;
    const int wave = tid >> 6, lane = tid & 63;
    const int quad = lane >> 4, l16 = lane & 15;
    const int wm = wave >> 1, wn = wave & 1;
    const int bm = blockIdx.y * 128, bn = blockIdx.x * 128;

    floatx4 acc[4][4] = {};
    for (int k0 = 0; k0 < K; k0 += 32) {
        #pragma unroll
        for (int i = 0; i < 2; ++i) {
            int c = wave * 128 + i * 64 + lane;
            int row = c >> 2, off = (c & 3) * 8;
            gload_lds16(A  + (size_t)(bm + row) * lda + k0 + off, As + (size_t)(wave * 128 + i * 64) * 8);
            gload_lds16(Bt + (size_t)(bn + row) * ldb + k0 + off, Bs + (size_t)(wave * 128 + i * 64) * 8);
        }
        __syncthreads();
        short8 a[4], b[4];
        #pragma unroll
        for (int mi = 0; mi < 4; ++mi)
            a[mi] = *(const short8*)&As[(wm * 64 + mi * 16 + l16) * 32 + quad * 8];
        #pragma unroll
        for (int ni = 0; ni < 4; ++ni)
            b[ni] = *(const short8*)&Bs[(wn * 64 + ni * 16 + l16) * 32 + quad * 8];
        #pragma unroll
        for (int mi = 0; mi < 4; ++mi)
            #pragma unroll
            for (int ni = 0; ni < 4; ++ni)
                acc[mi][ni] = __builtin_amdgcn_mfma_f32_16x16x32_bf16(a[mi], b[ni], acc[mi][ni], 0, 0, 0);
        __syncthreads();
    }
    #pragma unroll
    for (int mi = 0; mi < 4; ++mi)
        #pragma unroll
        for (int ni = 0; ni < 4; ++ni)
            #pragma unroll
            for (int r = 0; r < 4; ++r) {
                int row = bm + wm * 64 + mi * 16 + quad * 4 + r;
                int col = bn + wn * 64 + ni * 16 + l16;
                if (C_BF16)
                    ((unsigned short*)Cptr)[(size_t)row * ldc + col] = f2bf(acc[mi][ni][r]);
                else
                    ((float*)Cptr)[(size_t)row * ldc + col] = acc[mi][ni][r];
            }
}

// ====== 256x256-tile pipelined bf16 GEMM: C[M,N] = A[M,K] @ Bt[N,K]^T ======
// BK=32, 4 LDS K-tile buffers (128 KiB), staging 3 tiles ahead, counted
// s_waitcnt vmcnt(12), raw s_barrier, setprio, XCD-chunked swizzle.
template<bool C_BF16>
__global__ __launch_bounds__(512, 2) void gemm256(const unsigned short* __restrict__ A, int lda,
                                                  const unsigned short* __restrict__ Bt, int ldb,
                                                  void* __restrict__ Cptr, int ldc, int K, int nbx) {
    __shared__ __align__(16) unsigned short lds[4 * 16384];   // 4 bufs x (A 16KB | B 16KB)
    const int tid  = threadIdx.x;
    const int wave = tid >> 6, lane = tid & 63;
    const int quad = lane >> 4, l16 = lane & 15;
    const int wm = wave >> 2, wn = wave & 3;

    // XCD-chunked bijective swizzle (gridDim.x % 8 == 0)
    const int cpx = gridDim.x >> 3;
    const int swz = (blockIdx.x & 7) * cpx + (blockIdx.x >> 3);
    const int by = swz / nbx, bx = swz % nbx;
    const int bm = by * 256, bn = bx * 256;

    // ---- staging source pointers (pre-swizzled global chunk per lane) ----
    // linear LDS chunk ch -> row = ch>>2, slot = ch&3, global col-chunk = slot^(row&3)
    const int ch0 = wave * 64 + lane;
    const int ch1 = 512 + ch0;
    const int ar0 = ch0 >> 2, ac0 = ((ch0 & 3) ^ (ar0 & 3)) * 8;
    const int ar1 = ch1 >> 2, ac1 = ((ch1 & 3) ^ (ar1 & 3)) * 8;
    const unsigned short* a0 = A  + (size_t)(bm + ar0) * lda + ac0;
    const unsigned short* a1 = A  + (size_t)(bm + ar1) * lda + ac1;
    const unsigned short* b0 = Bt + (size_t)(bn + ar0) * ldb + ac0;
    const unsigned short* b1 = Bt + (size_t)(bn + ar1) * ldb + ac1;
    const unsigned du0 = (unsigned)(wave * 64) * 8;        // wave-uniform LDS dest (ushorts)
    const unsigned du1 = (unsigned)(512 + wave * 64) * 8;

    auto stage = [&](int kofs, int sb) {
        gload_lds16(a0 + kofs, &lds[sb + du0]);
        gload_lds16(a1 + kofs, &lds[sb + du1]);
        gload_lds16(b0 + kofs, &lds[sb + 8192 + du0]);
        gload_lds16(b1 + kofs, &lds[sb + 8192 + du1]);
    };

    floatx4 acc[8][4] = {};
    const int arow = wm * 128 + l16;
    const int brow = wn * 64 + l16;
    const int sslot = (quad ^ (l16 & 3)) * 8;   // row&3 == l16&3 for 16-aligned tiles

    auto compute = [&](int cbo) {
        short8 bfr[4];
        #pragma unroll
        for (int ni = 0; ni < 4; ++ni)
            bfr[ni] = *(const short8*)&lds[cbo + 8192 + (brow + ni * 16) * 32 + sslot];
        __builtin_amdgcn_s_setprio(1);
        #pragma unroll
        for (int mi = 0; mi < 8; ++mi) {
            short8 afr = *(const short8*)&lds[cbo + (arow + mi * 16) * 32 + sslot];
            #pragma unroll
            for (int ni = 0; ni < 4; ++ni)
                acc[mi][ni] = __builtin_amdgcn_mfma_f32_16x16x32_bf16(afr, bfr[ni], acc[mi][ni], 0, 0, 0);
        }
        __builtin_amdgcn_s_setprio(0);
    };

    const int NT = K >> 5;                       // K-tiles of 32 (NT >= 4)
    // prologue: stage tiles 0,1,2
    stage(0,  0);
    stage(32, 16384);
    stage(64, 32768);

    int cb = 0;
    for (int t = 0; t < NT - 3; ++t) {
        stage((t + 3) * 32, (cb + 3 * 16384) & 65535);   // buf (t+3)&3 == (t-1)&3: freed by prev end-barrier
        asm volatile("s_waitcnt vmcnt(12)" ::: "memory"); // my 4 loads for tile t retired
        __builtin_amdgcn_s_barrier();                     // everyone's tile-t loads visible
        asm volatile("" ::: "memory");
        compute(cb);
        asm volatile("" ::: "memory");
        __builtin_amdgcn_s_barrier();                     // tile-t reads done before re-staging its buf
        cb = (cb + 16384) & 65535;
    }
    // tail: tiles NT-3, NT-2, NT-1 (no staging; drain 8 -> 4 -> 0)
    asm volatile("s_waitcnt vmcnt(8)" ::: "memory");
    __builtin_amdgcn_s_barrier();
    asm volatile("" ::: "memory");
    compute(cb);
    asm volatile("" ::: "memory");
    __builtin_amdgcn_s_barrier();
    cb = (cb + 16384) & 65535;

    asm volatile("s_waitcnt vmcnt(4)" ::: "memory");
    __builtin_amdgcn_s_barrier();
    asm volatile("" ::: "memory");
    compute(cb);
    asm volatile("" ::: "memory");
    __builtin_amdgcn_s_barrier();
    cb = (cb + 16384) & 65535;

    asm volatile("s_waitcnt vmcnt(0)" ::: "memory");
    __builtin_amdgcn_s_barrier();
    asm volatile("" ::: "memory");
    compute(cb);

    // ---- epilogue: C[row, col], row from A-frag (quad*4+r), col from B-frag (l16)
    #pragma unroll
    for (int mi = 0; mi < 8; ++mi)
        #pragma unroll
        for (int ni = 0; ni < 4; ++ni)
            #pragma unroll
            for (int r = 0; r < 4; ++r) {
                int row = bm + wm * 128 + mi * 16 + quad * 4 + r;
                int col = bn + wn * 64 + ni * 16 + l16;
                if (C_BF16)
                    ((unsigned short*)Cptr)[(size_t)row * ldc + col] = f2bf(acc[mi][ni][r]);
                else
                    ((float*)Cptr)[(size_t)row * ldc + col] = acc[mi][ni][r];
            }
}

// ============ per-head RMSNorm + RoPE; q additionally scaled by QSCALE =====
__global__ __launch_bounds__(256) void rms_rope_bf16(unsigned short* __restrict__ qkv,
                                                     const int* __restrict__ positions,
                                                     const float* __restrict__ qw,
                                                     const float* __restrict__ kw) {
    const int t = blockIdx.x;
    const int wave = threadIdx.x >> 6;
    const int lane = threadIdx.x & 63;
    const float pos = (float)positions[t];
    unsigned short* row = qkv + (size_t)t * QKV_W;
    // 1e6^(-lane/64) = exp2(-lane * log2(1e6)/64)
    const float inv_freq = exp2f(-(float)lane * (19.931568569324174f / 64.0f));
    float sv, cv;
    sincosf(pos * inv_freq, &sv, &cv);
    for (int h = wave; h < NH + NKV; h += 4) {
        unsigned short* x = row + h * HD;
        const float* w = (h < NH) ? qw : kw;
        const float hs = (h < NH) ? QSCALE : 1.0f;
        float x1 = bf2f(x[lane]);
        float x2 = bf2f(x[lane + 64]);
        float ss = x1 * x1 + x2 * x2;
        #pragma unroll
        for (int off = 32; off > 0; off >>= 1) ss += __shfl_xor(ss, off, 64);
        float r = rsqrtf(ss * (1.0f / 128.0f) + EPS) * hs;
        float n1 = x1 * r * w[lane];
        float n2 = x2 * r * w[lane + 64];
        x[lane]      = f2bf(n1 * cv - n2 * sv);
        x[lane + 64] = f2bf(n2 * cv + n1 * sv);
    }
}

// ====== KV pre-pack: per kvh, per 128-token tile, contiguous 32 KB tiles ===
// Kp tile: chunk (s, c) -> slot s*16 + (c ^ (s&7))           [s=token, c=dim/8]
// Vp tile: V^T chunk (d, cs) -> slot d*16 + (cs ^ (d&7)); within-chunk halves
//          (2x 4 tokens) swapped iff (d>>3)&1  -> conflict-free b64 reads
__global__ __launch_bounds__(256) void kv_pack(const unsigned short* __restrict__ qkv,
                                               unsigned short* __restrict__ Kp,
                                               unsigned short* __restrict__ Vp) {
    const int tile = blockIdx.x, kvh = blockIdx.y, tid = threadIdx.x;
    const int t0 = tile * 128;
    const size_t tb = (size_t)(kvh * 32 + tile) * 16384;
    // ---- K: swizzle chunks within each row
    #pragma unroll
    for (int i = 0; i < 8; ++i) {
        int cid = i * 256 + tid;
        int s = cid >> 4, c = cid & 15;
        short8 v = *(const short8*)&qkv[(size_t)(t0 + s) * QKV_W + QS + kvh * HD + c * 8];
        *(short8*)&Kp[tb + (s * 16 + (c ^ (s & 7))) * 8] = v;
    }
    // ---- V: transpose via LDS
    __shared__ __align__(16) unsigned short Lt[128 * 136];
    #pragma unroll
    for (int i = 0; i < 8; ++i) {
        int cid = i * 256 + tid;
        int s = cid >> 4, c = cid & 15;
        short8 v = *(const short8*)&qkv[(size_t)(t0 + s) * QKV_W + QS + KVS + kvh * HD + c * 8];
        // rotated element order: lanes with different c hit different banks
        // (straight e-order is a 32-way conflict: 1088*c/2 mod 32 == 0)
        #pragma unroll
        for (int e = 0; e < 8; ++e) {
            int ee = (e + c) & 7;
            Lt[(c * 8 + ee) * 136 + s] = (unsigned short)v[ee];
        }
    }
    __syncthreads();
    #pragma unroll
    for (int i = 0; i < 8; ++i) {
        int cid = i * 256 + tid;
        int d = cid >> 4, cs = cid & 15;
        short8 v = *(const short8*)&Lt[d * 136 + cs * 8];
        short8 w;
        if ((d >> 3) & 1) {
            #pragma unroll
            for (int e = 0; e < 8; ++e) w[e] = v[e ^ 4];   // swap 4-token halves
        } else w = v;
        *(short8*)&Vp[tb + (d * 16 + (cs ^ (d & 7))) * 8] = w;
    }
}

// ================= MFMA causal GQA flash attention =========================
// Transposed-S scheme (S^T = K·Q^T); 128 q-rows/block, 128 kv/step.
// 8 waves x 16 q-rows (512 thr): 2 blocks/CU x 8 waves = 16 waves/CU
// (4/SIMD) -- doubles latency/barrier hiding vs the 4-wave version.
// LDS Ks+Vs = 64 KB. Balanced pairing: blocks (c, c+256) get qt and 31-qt.
__global__ __launch_bounds__(512, 4) void attn_mfma(unsigned short* __restrict__ qkv,
                                                    const unsigned short* __restrict__ Kp,
                                                    const unsigned short* __restrict__ Vp) {
    __shared__ __align__(16) unsigned short Ks[128 * 128];
    __shared__ __align__(16) unsigned short Vs[128 * 128];
    const int bx = blockIdx.x;
    const int h = bx & 15, kvh = h >> 1;            // XCD = bx%8 tracks h%8
    const int g = bx >> 4;                          // 0..31
    const int qt = (g < 16) ? (31 - g) : (g - 16);  // pair sums = 31
    const int tid = threadIdx.x;
    const int wave = tid >> 6, lane = tid & 63;
    const int quad = lane >> 4, l16 = lane & 15;
    const int t0 = qt * 128;
    const int wrow0 = t0 + wave * 16;               // 16 q-rows per wave
    const int swz = l16 & 7;
    const int hsel = (l16 >> 3) & 1;                // V half-swap selector
    const int vhalf = ((quad & 1) ^ hsel) * 4;
    const int q2 = quad >> 1;

    // Q fragments (pre-scaled by QSCALE); B-operand of K·Q^T
    short8 qf[4];
    #pragma unroll
    for (int ks = 0; ks < 4; ++ks) {
        int rowg = wrow0 + l16;
        qf[ks] = *(const short8*)&qkv[(size_t)rowg * QKV_W + h * HD + ks * 32 + quad * 8];
    }

    float l_s = 0.0f;
    floatx4 oacc[8] = {};

    for (int st = 0; st <= qt; ++st) {
        const int s0 = st * 128;
        const unsigned short* kb = Kp + (size_t)(kvh * 32 + st) * 16384;
        const unsigned short* vb = Vp + (size_t)(kvh * 32 + st) * 16384;
        #pragma unroll
        for (int i = 0; i < 4; ++i) {
            int ch = i * 512 + tid;
            gload_lds16(kb + (size_t)ch * 8, Ks + (i * 512 + wave * 64) * 8);
        }
        #pragma unroll
        for (int i = 0; i < 4; ++i) {
            int ch = i * 512 + tid;
            gload_lds16(vb + (size_t)ch * 8, Vs + (i * 512 + wave * 64) * 8);
        }
        __syncthreads();   // bar1: staging visible

        const bool diag = (st == qt);
        #pragma unroll
        for (int ct = 0; ct < 8; ++ct) {
            const int smin = s0 + ct * 16;
            if (diag && smin > wrow0 + 15) continue;   // wave-uniform causal skip
            // ---- S^T block: C[s=quad*4+r][t=l16]
            floatx4 sacc = {};
            #pragma unroll
            for (int ks = 0; ks < 4; ++ks) {
                short8 kfr = *(const short8*)&Ks[(ct * 16 + l16) * 128 + ((ks * 4 + quad) ^ swz) * 8];
                sacc = __builtin_amdgcn_mfma_f32_16x16x32_bf16(kfr, qf[ks], sacc, 0, 0, 0);
            }
            // ---- exp2 + pack into PV A-fragment
            const int tg = wrow0 + l16;
            float p[4];
            float lsum = 0.0f;
            #pragma unroll
            for (int r = 0; r < 4; ++r) {
                float s = sacc[r];
                if (diag && (smin + quad * 4 + r > tg)) s = -1e30f;
                p[r] = EXP2(s);
                lsum += p[r];
            }
            l_s += lsum;
            union { short4v s4; unsigned int u[2]; } pk;
            pk.u[0] = pk2(p[0], p[1]);
            pk.u[1] = pk2(p[2], p[3]);
            short4v pp = pk.s4;
            // ---- O += P V  (K=16 MFMA; conflict-free b64 V reads)
            const int vc = (((ct * 2 + q2) ^ swz)) * 8 + vhalf;
#if __has_builtin(__builtin_amdgcn_mfma_f32_16x16x16bf16_1k)
            #pragma unroll
            for (int dct = 0; dct < 8; ++dct) {
                short4v bfr = *(const short4v*)&Vs[(dct * 16 + l16) * 128 + vc];
                oacc[dct] = __builtin_amdgcn_mfma_f32_16x16x16bf16_1k(pp, bfr, oacc[dct], 0, 0, 0);
            }
#else
            #pragma unroll
            for (int dct = 0; dct < 8; ++dct) {
                union { short8 s8; short4v s4[2]; } b;
                b.s4[0] = *(const short4v*)&Vs[(dct * 16 + l16) * 128 + vc];
                b.s4[1] = short4v{0, 0, 0, 0};
                union { short8 s8; short4v s4[2]; } a;
                a.s4[0] = pp;
                a.s4[1] = short4v{0, 0, 0, 0};
                oacc[dct] = __builtin_amdgcn_mfma_f32_16x16x32_bf16(a.s8, b.s8, oacc[dct], 0, 0, 0);
            }
#endif
        }
        __syncthreads();   // bar2: Ks/Vs reads done before next staging
    }

    // ---- epilogue: reduce l across quads, redistribute, normalize, store
    float lred = l_s;
    lred += __shfl_xor(lred, 16, 64);
    lred += __shfl_xor(lred, 32, 64);              // valid for t = l16 in all quads
    #pragma unroll
    for (int r = 0; r < 4; ++r) {
        float l = __shfl(lred, quad * 4 + r, 64);
        float linv = 1.0f / l;
        int rowg = wrow0 + quad * 4 + r;
        #pragma unroll
        for (int dct = 0; dct < 8; ++dct)
            qkv[(size_t)rowg * QKV_W + h * HD + dct * 16 + l16] = f2bf(oacc[dct][r] * linv);
    }
}

extern "C" void kernel_launch(void* const* d_in, const int* in_sizes, int n_in,
                              void* d_out, int out_size, void* d_ws, size_t ws_size,
                              hipStream_t stream) {
    const int*   positions = (const int*)d_in[0];
    const float* hidden    = (const float*)d_in[1];
    const float* w_qkv     = (const float*)d_in[2];
    const float* w_o       = (const float*)d_in[3];
    const float* q_norm_w  = (const float*)d_in[4];
    const float* k_norm_w  = (const float*)d_in[5];
    float* out = (float*)d_out;

    unsigned short* qkvb   = (unsigned short*)d_ws;
    unsigned short* h_bf   = (unsigned short*)((char*)d_ws + ((size_t)32 << 20));
    unsigned short* Kp     = (unsigned short*)((char*)d_ws + ((size_t)32 << 20));
    unsigned short* Vp     = (unsigned short*)((char*)d_ws + ((size_t)40 << 20));
    unsigned short* wqkv_t = (unsigned short*)((char*)d_ws + ((size_t)48 << 20));
    unsigned short* wo_t   = (unsigned short*)((char*)d_ws + ((size_t)48 << 20));

    cvt_bf16<<<(T_TOK * H_DIM) / (256 * 8), 256, 0, stream>>>(hidden, h_bf);
    cvt_transpose<<<dim3(QKV_W / 64, H_DIM / 64), 256, 0, stream>>>(w_qkv, wqkv_t, H_DIM, QKV_W);
    // QKV: M=4096, N=4096, K=2048 -> grid 16*16 = 256 blocks (%8==0)
    gemm256<true><<<dim3(256), 512, 0, stream>>>(
        h_bf, H_DIM, wqkv_t, H_DIM, qkvb, QKV_W, H_DIM, QKV_W / 256);
    rms_rope_bf16<<<T_TOK, 256, 0, stream>>>(qkvb, positions, q_norm_w, k_norm_w);
    kv_pack<<<dim3(T_TOK / 128, NKV), 256, 0, stream>>>(qkvb, Kp, Vp);
    cvt_transpose<<<dim3(H_DIM / 64, QS / 64), 256, 0, stream>>>(w_o, wo_t, QS, H_DIM);
    attn_mfma<<<512, 512, 0, stream>>>(qkvb, Kp, Vp);
    // WO: M=4096, N=2048, K=2048 -> 128^2 tiles, 512 blocks (2/CU, all CUs busy)
    gemm_bt<false><<<dim3(H_DIM / 128, T_TOK / 128), 256, 0, stream>>>(
        qkvb, QKV_W, wo_t, QS, out, H_DIM, QS);
}

// Round 6
// 369.624 us; speedup vs baseline: 1.0474x; 1.0474x over previous
//
#include <hip/hip_runtime.h>
#include <hip/hip_bf16.h>
#include <math.h>

#define T_TOK 4096
#define H_DIM 2048
#define NH 16
#define NKV 8
#define HD 128
#define QS (NH * HD)        // 2048
#define KVS (NKV * HD)      // 1024
#define QKV_W (QS + 2*KVS)  // 4096
// SCALE * log2(e): Q pre-scaled so softmax runs in exp2 domain
#define QSCALE (0.08838834764831845f * 1.4426950408889634f)
#define EPS 1e-6f

typedef short short8 __attribute__((ext_vector_type(8)));
typedef short short4v __attribute__((ext_vector_type(4)));
typedef float floatx4 __attribute__((ext_vector_type(4)));

#if __has_builtin(__builtin_amdgcn_exp2f)
#define EXP2(x) __builtin_amdgcn_exp2f(x)
#else
#define EXP2(x) exp2f(x)
#endif

__device__ __forceinline__ unsigned short f2bf(float f) {
    unsigned int u = __float_as_uint(f);
    unsigned int r = (u + 0x7FFFu + ((u >> 16) & 1u)) >> 16;   // RNE
    return (unsigned short)r;
}
__device__ __forceinline__ float bf2f(unsigned short u) {
    unsigned int v = ((unsigned int)u) << 16;
    return __uint_as_float(v);
}
// packed f32x2 -> bf16x2
__device__ __forceinline__ unsigned int pk2(float a, float b) {
    union { __hip_bfloat162 h; unsigned int u; } c;
    c.h = __float22bfloat162_rn(make_float2(a, b));
    return c.u;
}

// async global->LDS 16B: LDS dest is wave-uniform base + lane*16
__device__ __forceinline__ void gload_lds16(const unsigned short* g, unsigned short* l) {
    __builtin_amdgcn_global_load_lds(
        (const __attribute__((address_space(1))) unsigned int*)(const void*)g,
        (__attribute__((address_space(3))) unsigned int*)(void*)l, 16, 0, 0);
}

// ---------------- f32 -> bf16 flat convert ---------------------------------
__global__ __launch_bounds__(256) void cvt_bf16(const float* __restrict__ in,
                                                unsigned short* __restrict__ out) {
    int idx = (blockIdx.x * 256 + threadIdx.x) * 8;
    float4 v0 = *(const float4*)&in[idx];
    float4 v1 = *(const float4*)&in[idx + 4];
    short8 t;
    t[0] = (short)f2bf(v0.x); t[1] = (short)f2bf(v0.y);
    t[2] = (short)f2bf(v0.z); t[3] = (short)f2bf(v0.w);
    t[4] = (short)f2bf(v1.x); t[5] = (short)f2bf(v1.y);
    t[6] = (short)f2bf(v1.z); t[7] = (short)f2bf(v1.w);
    *(short8*)&out[idx] = t;
}

// ------------- f32 [K][N] -> bf16 [N][K] transpose+convert -----------------
__global__ __launch_bounds__(256) void cvt_transpose(const float* __restrict__ in,
                                                     unsigned short* __restrict__ out,
                                                     int K, int N) {
    __shared__ __align__(16) unsigned short t[64][72];
    const int tid = threadIdx.x;
    const int n0 = blockIdx.x * 64, k0 = blockIdx.y * 64;
    const int r = tid >> 4, c4 = (tid & 15) * 4;
    #pragma unroll
    for (int i = 0; i < 4; ++i) {
        int kk = r + 16 * i;
        float4 v = *(const float4*)&in[(size_t)(k0 + kk) * N + n0 + c4];
        t[c4 + 0][kk] = f2bf(v.x); t[c4 + 1][kk] = f2bf(v.y);
        t[c4 + 2][kk] = f2bf(v.z); t[c4 + 3][kk] = f2bf(v.w);
    }
    __syncthreads();
    const int n = tid >> 2, c8 = (tid & 3) * 16;
    short8 a = *(const short8*)&t[n][c8];
    short8 b = *(const short8*)&t[n][c8 + 8];
    *(short8*)&out[(size_t)(n0 + n) * K + k0 + c8] = a;
    *(short8*)&out[(size_t)(n0 + n) * K + k0 + c8 + 8] = b;
}

// ====== m97-style bf16 GEMM: C[M,N] = A[M,K] @ Bt[N,K]^T, global_load_lds ==
template<bool C_BF16>
__global__ __launch_bounds__(256) void gemm_bt(const unsigned short* __restrict__ A, int lda,
                                               const unsigned short* __restrict__ Bt, int ldb,
                                               void* __restrict__ Cptr, int ldc, int K) {
    __shared__ __align__(16) unsigned short As[128 * 32];
    __shared__ __align__(16) unsigned short Bs[128 * 32];
    const int tid = threadIdx.x;
    const int wave = tid >> 6, lane = tid & 63;
    const int quad = lane >> 4, l16 = lane & 15;
    const int wm = wave >> 1, wn = wave & 1;
    const int bm = blockIdx.y * 128, bn = blockIdx.x * 128;

    floatx4 acc[4][4] = {};
    for (int k0 = 0; k0 < K; k0 += 32) {
        #pragma unroll
        for (int i = 0; i < 2; ++i) {
            int c = wave * 128 + i * 64 + lane;
            int row = c >> 2, off = (c & 3) * 8;
            gload_lds16(A  + (size_t)(bm + row) * lda + k0 + off, As + (size_t)(wave * 128 + i * 64) * 8);
            gload_lds16(Bt + (size_t)(bn + row) * ldb + k0 + off, Bs + (size_t)(wave * 128 + i * 64) * 8);
        }
        __syncthreads();
        short8 a[4], b[4];
        #pragma unroll
        for (int mi = 0; mi < 4; ++mi)
            a[mi] = *(const short8*)&As[(wm * 64 + mi * 16 + l16) * 32 + quad * 8];
        #pragma unroll
        for (int ni = 0; ni < 4; ++ni)
            b[ni] = *(const short8*)&Bs[(wn * 64 + ni * 16 + l16) * 32 + quad * 8];
        #pragma unroll
        for (int mi = 0; mi < 4; ++mi)
            #pragma unroll
            for (int ni = 0; ni < 4; ++ni)
                acc[mi][ni] = __builtin_amdgcn_mfma_f32_16x16x32_bf16(a[mi], b[ni], acc[mi][ni], 0, 0, 0);
        __syncthreads();
    }
    #pragma unroll
    for (int mi = 0; mi < 4; ++mi)
        #pragma unroll
        for (int ni = 0; ni < 4; ++ni)
            #pragma unroll
            for (int r = 0; r < 4; ++r) {
                int row = bm + wm * 64 + mi * 16 + quad * 4 + r;
                int col = bn + wn * 64 + ni * 16 + l16;
                if (C_BF16)
                    ((unsigned short*)Cptr)[(size_t)row * ldc + col] = f2bf(acc[mi][ni][r]);
                else
                    ((float*)Cptr)[(size_t)row * ldc + col] = acc[mi][ni][r];
            }
}

// ====== 256x256 8-phase pipelined bf16 GEMM (m201 structure, plain HIP) ====
// C[M,N] = A[M,K] @ Bt[N,K]^T.  BK=64, 2 LDS buffers of (A[256][64]|B[256][64])
// = 128 KiB -> 1 block/CU, 8 waves (2M x 4N).  Per K-tile: 4 phases, each
// {ds_read frags ; stage one 16KB half-tile ; barrier ; lgkmcnt(0) ; setprio ;
// 16 MFMA ; setprio ; barrier}.  vmcnt(2) only at phase 0 (tail: vmcnt(0)).
// Chunk swizzle: LDS (row, slot) holds global 16B-chunk slot^(row&7), applied
// on BOTH sides (pre-swizzled global source + swizzled ds_read address).
template<bool C_BF16>
__global__ __launch_bounds__(512, 2) void gemm8p(const unsigned short* __restrict__ A, int lda,
                                                 const unsigned short* __restrict__ Bt, int ldb,
                                                 void* __restrict__ Cptr, int ldc, int K, int nbx) {
    __shared__ __align__(16) unsigned short lds[2 * 32768];   // 2 x (A 32KB | B 32KB)
    const int tid  = threadIdx.x;
    const int wave = tid >> 6, lane = tid & 63;
    const int quad = lane >> 4, l16 = lane & 15;
    const int wm = wave >> 2, wn = wave & 3;

    // XCD-chunked bijective swizzle (gridDim.x % 8 == 0)
    const int cpx = gridDim.x >> 3;
    const int swzb = (blockIdx.x & 7) * cpx + (blockIdx.x >> 3);
    const int by = swzb / nbx, bx = swzb % nbx;
    const int bm = by * 256, bn = bx * 256;

    // staging per-thread invariants: 2 chunks/thread per half-tile (1024 chunks)
    const int ch0 = wave * 64 + lane, ch1 = 512 + ch0;
    const int r0 = ch0 >> 3, gc0 = ((ch0 & 7) ^ (r0 & 7)) * 8;
    const int r1 = ch1 >> 3, gc1 = ((ch1 & 7) ^ (r1 & 7)) * 8;
    const unsigned du0 = (unsigned)(wave * 64) * 8;
    const unsigned du1 = (unsigned)(512 + wave * 64) * 8;

    // stage half-tile hf (0:A rows 0-127, 1:B 0-127, 2:A 128-255, 3:B 128-255)
    auto stage = [&](int kt, int hf, int buf) {
        const int panel = hf & 1, rhalf = (hf >> 1) * 128;
        const unsigned short* P = panel ? Bt : A;
        const int bp = panel ? bn : bm;
        const int ld = panel ? ldb : lda;
        unsigned short* dst = &lds[buf * 32768 + panel * 16384 + rhalf * 64];
        gload_lds16(P + (size_t)(bp + rhalf + r0) * ld + kt * 64 + gc0, dst + du0);
        gload_lds16(P + (size_t)(bp + rhalf + r1) * ld + kt * 64 + gc1, dst + du1);
    };

    floatx4 acc[8][4] = {};
    const int arowb = wm * 128 + l16;
    const int browb = wn * 64 + l16;
    const int sw = l16 & 7;

    short8 bfr[4], afr[4];
    auto rdB = [&](int cur, int kk) {
        const int sl = ((kk * 4 + quad) ^ sw) * 8;
        #pragma unroll
        for (int ni = 0; ni < 4; ++ni)
            bfr[ni] = *(const short8*)&lds[cur * 32768 + 16384 + (browb + ni * 16) * 64 + sl];
    };
    auto rdA = [&](int cur, int mh, int kk) {
        const int sl = ((kk * 4 + quad) ^ sw) * 8;
        #pragma unroll
        for (int mi = 0; mi < 4; ++mi)
            afr[mi] = *(const short8*)&lds[cur * 32768 + (arowb + (mh * 4 + mi) * 16) * 64 + sl];
    };
    auto mfma16 = [&](int mh) {
        asm volatile("s_waitcnt lgkmcnt(0)" ::: "memory");
        __builtin_amdgcn_s_setprio(1);
        #pragma unroll
        for (int mi = 0; mi < 4; ++mi)
            #pragma unroll
            for (int ni = 0; ni < 4; ++ni)
                acc[mh * 4 + mi][ni] =
                    __builtin_amdgcn_mfma_f32_16x16x32_bf16(afr[mi], bfr[ni], acc[mh * 4 + mi][ni], 0, 0, 0);
        __builtin_amdgcn_s_setprio(0);
    };

    const int NT = K >> 6;                        // K-tiles of 64
    // prologue: stage all 4 halves of tile 0 into buf 0
    stage(0, 0, 0); stage(0, 1, 0); stage(0, 2, 0); stage(0, 3, 0);

    int cur = 0;
    for (int kt = 0; kt < NT; ++kt) {
        const bool last = (kt == NT - 1);
        // ---- phase 0: (mh=0, kk=0); only phase with a vmcnt
        if (!last) {
            stage(kt + 1, 0, cur ^ 1);
            asm volatile("s_waitcnt vmcnt(2)" ::: "memory");  // tile-kt loads retired
        } else {
            asm volatile("s_waitcnt vmcnt(0)" ::: "memory");
        }
        __builtin_amdgcn_s_barrier();                          // all waves' tile-kt data visible
        rdB(cur, 0); rdA(cur, 0, 0);
        mfma16(0);
        __builtin_amdgcn_s_barrier();
        // ---- phase 1: (mh=1, kk=0)
        rdA(cur, 1, 0);
        if (!last) stage(kt + 1, 1, cur ^ 1);
        __builtin_amdgcn_s_barrier();
        mfma16(1);
        __builtin_amdgcn_s_barrier();
        // ---- phase 2: (mh=0, kk=1)
        rdB(cur, 1); rdA(cur, 0, 1);
        if (!last) stage(kt + 1, 2, cur ^ 1);
        __builtin_amdgcn_s_barrier();
        mfma16(0);
        __builtin_amdgcn_s_barrier();
        // ---- phase 3: (mh=1, kk=1)
        rdA(cur, 1, 1);
        if (!last) stage(kt + 1, 3, cur ^ 1);
        __builtin_amdgcn_s_barrier();
        mfma16(1);
        __builtin_amdgcn_s_barrier();
        cur ^= 1;
    }

    // ---- epilogue: C[row, col]
    #pragma unroll
    for (int mi = 0; mi < 8; ++mi)
        #pragma unroll
        for (int ni = 0; ni < 4; ++ni)
            #pragma unroll
            for (int r = 0; r < 4; ++r) {
                int row = bm + wm * 128 + mi * 16 + quad * 4 + r;
                int col = bn + wn * 64 + ni * 16 + l16;
                if (C_BF16)
                    ((unsigned short*)Cptr)[(size_t)row * ldc + col] = f2bf(acc[mi][ni][r]);
                else
                    ((float*)Cptr)[(size_t)row * ldc + col] = acc[mi][ni][r];
            }
}

// ============ per-head RMSNorm + RoPE; q additionally scaled by QSCALE =====
__global__ __launch_bounds__(256) void rms_rope_bf16(unsigned short* __restrict__ qkv,
                                                     const int* __restrict__ positions,
                                                     const float* __restrict__ qw,
                                                     const float* __restrict__ kw) {
    const int t = blockIdx.x;
    const int wave = threadIdx.x >> 6;
    const int lane = threadIdx.x & 63;
    const float pos = (float)positions[t];
    unsigned short* row = qkv + (size_t)t * QKV_W;
    // 1e6^(-lane/64) = exp2(-lane * log2(1e6)/64)
    const float inv_freq = exp2f(-(float)lane * (19.931568569324174f / 64.0f));
    float sv, cv;
    sincosf(pos * inv_freq, &sv, &cv);
    for (int h = wave; h < NH + NKV; h += 4) {
        unsigned short* x = row + h * HD;
        const float* w = (h < NH) ? qw : kw;
        const float hs = (h < NH) ? QSCALE : 1.0f;
        float x1 = bf2f(x[lane]);
        float x2 = bf2f(x[lane + 64]);
        float ss = x1 * x1 + x2 * x2;
        #pragma unroll
        for (int off = 32; off > 0; off >>= 1) ss += __shfl_xor(ss, off, 64);
        float r = rsqrtf(ss * (1.0f / 128.0f) + EPS) * hs;
        float n1 = x1 * r * w[lane];
        float n2 = x2 * r * w[lane + 64];
        x[lane]      = f2bf(n1 * cv - n2 * sv);
        x[lane + 64] = f2bf(n2 * cv + n1 * sv);
    }
}

// ====== KV pre-pack: per kvh, per 128-token tile, contiguous 32 KB tiles ===
// Kp tile: chunk (s, c) -> slot s*16 + (c ^ (s&7))           [s=token, c=dim/8]
// Vp tile: V^T chunk (d, cs) -> slot d*16 + (cs ^ (d&7)); within-chunk halves
//          (2x 4 tokens) swapped iff (d>>3)&1  -> conflict-free b64 reads
__global__ __launch_bounds__(256) void kv_pack(const unsigned short* __restrict__ qkv,
                                               unsigned short* __restrict__ Kp,
                                               unsigned short* __restrict__ Vp) {
    const int tile = blockIdx.x, kvh = blockIdx.y, tid = threadIdx.x;
    const int t0 = tile * 128;
    const size_t tb = (size_t)(kvh * 32 + tile) * 16384;
    // ---- K: swizzle chunks within each row
    #pragma unroll
    for (int i = 0; i < 8; ++i) {
        int cid = i * 256 + tid;
        int s = cid >> 4, c = cid & 15;
        short8 v = *(const short8*)&qkv[(size_t)(t0 + s) * QKV_W + QS + kvh * HD + c * 8];
        *(short8*)&Kp[tb + (s * 16 + (c ^ (s & 7))) * 8] = v;
    }
    // ---- V: transpose via LDS
    __shared__ __align__(16) unsigned short Lt[128 * 136];
    #pragma unroll
    for (int i = 0; i < 8; ++i) {
        int cid = i * 256 + tid;
        int s = cid >> 4, c = cid & 15;
        short8 v = *(const short8*)&qkv[(size_t)(t0 + s) * QKV_W + QS + KVS + kvh * HD + c * 8];
        // rotated element order: lanes with different c hit different banks
        #pragma unroll
        for (int e = 0; e < 8; ++e) {
            int ee = (e + c) & 7;
            Lt[(c * 8 + ee) * 136 + s] = (unsigned short)v[ee];
        }
    }
    __syncthreads();
    #pragma unroll
    for (int i = 0; i < 8; ++i) {
        int cid = i * 256 + tid;
        int d = cid >> 4, cs = cid & 15;
        short8 v = *(const short8*)&Lt[d * 136 + cs * 8];
        short8 w;
        if ((d >> 3) & 1) {
            #pragma unroll
            for (int e = 0; e < 8; ++e) w[e] = v[e ^ 4];   // swap 4-token halves
        } else w = v;
        *(short8*)&Vp[tb + (d * 16 + (cs ^ (d & 7))) * 8] = w;
    }
}

// ================= MFMA causal GQA flash attention =========================
// Transposed-S scheme (S^T = K·Q^T); 128 q-rows/block, 128 kv/step.
// ct-interleaved: per 16-col block do QK^T -> exp2/pack -> PV immediately.
// LDS Ks+Vs = 64 KB -> 2 blocks/CU. Balanced pairing: blocks (c, c+256)
// get qt and 31-qt.  (round-4 version: 114.6 us, MfmaUtil 37%)
__global__ __launch_bounds__(256, 2) void attn_mfma(unsigned short* __restrict__ qkv,
                                                    const unsigned short* __restrict__ Kp,
                                                    const unsigned short* __restrict__ Vp) {
    __shared__ __align__(16) unsigned short Ks[128 * 128];
    __shared__ __align__(16) unsigned short Vs[128 * 128];
    const int bx = blockIdx.x;
    const int h = bx & 15, kvh = h >> 1;            // XCD = bx%8 tracks h%8
    const int g = bx >> 4;                          // 0..31
    const int qt = (g < 16) ? (31 - g) : (g - 16);  // pair sums = 31
    const int tid = threadIdx.x;
    const int wave = tid >> 6, lane = tid & 63;
    const int quad = lane >> 4, l16 = lane & 15;
    const int t0 = qt * 128;
    const int wrow0 = t0 + wave * 32;
    const int swz = l16 & 7;
    const int hsel = (l16 >> 3) & 1;                // V half-swap selector
    const int vhalf = ((quad & 1) ^ hsel) * 4;
    const int q2 = quad >> 1;

    // Q fragments (pre-scaled by QSCALE); B-operand of K·Q^T
    short8 qf[2][4];
    #pragma unroll
    for (int rt = 0; rt < 2; ++rt)
        #pragma unroll
        for (int ks = 0; ks < 4; ++ks) {
            int rowg = t0 + wave * 32 + rt * 16 + l16;
            qf[rt][ks] = *(const short8*)&qkv[(size_t)rowg * QKV_W + h * HD + ks * 32 + quad * 8];
        }

    float l_s[2] = {};
    floatx4 oacc[2][8] = {};

    for (int st = 0; st <= qt; ++st) {
        const int s0 = st * 128;
        const unsigned short* kb = Kp + (size_t)(kvh * 32 + st) * 16384;
        const unsigned short* vb = Vp + (size_t)(kvh * 32 + st) * 16384;
        #pragma unroll
        for (int i = 0; i < 8; ++i) {
            int ch = i * 256 + tid;
            gload_lds16(kb + (size_t)ch * 8, Ks + (i * 256 + wave * 64) * 8);
        }
        #pragma unroll
        for (int i = 0; i < 8; ++i) {
            int ch = i * 256 + tid;
            gload_lds16(vb + (size_t)ch * 8, Vs + (i * 256 + wave * 64) * 8);
        }
        __syncthreads();   // bar1: staging visible

        const bool diag = (st == qt);
        #pragma unroll
        for (int ct = 0; ct < 8; ++ct) {
            const int smin = s0 + ct * 16;
            if (diag && smin > wrow0 + 31) continue;   // wave-uniform causal skip
            // ---- S^T block: C[s=quad*4+r][t=l16 (+16rt)]
            floatx4 sacc[2] = {};
            #pragma unroll
            for (int ks = 0; ks < 4; ++ks) {
                short8 kfr = *(const short8*)&Ks[(ct * 16 + l16) * 128 + ((ks * 4 + quad) ^ swz) * 8];
                sacc[0] = __builtin_amdgcn_mfma_f32_16x16x32_bf16(kfr, qf[0][ks], sacc[0], 0, 0, 0);
                sacc[1] = __builtin_amdgcn_mfma_f32_16x16x32_bf16(kfr, qf[1][ks], sacc[1], 0, 0, 0);
            }
            // ---- exp2 + pack into PV A-fragments
            short4v pp[2];
            #pragma unroll
            for (int rt = 0; rt < 2; ++rt) {
                const int tg = wrow0 + rt * 16 + l16;
                float p[4];
                float lsum = 0.0f;
                #pragma unroll
                for (int r = 0; r < 4; ++r) {
                    float s = sacc[rt][r];
                    if (diag && (smin + quad * 4 + r > tg)) s = -1e30f;
                    p[r] = EXP2(s);
                    lsum += p[r];
                }
                l_s[rt] += lsum;
                union { short4v s4; unsigned int u[2]; } pk;
                pk.u[0] = pk2(p[0], p[1]);
                pk.u[1] = pk2(p[2], p[3]);
                pp[rt] = pk.s4;
            }
            // ---- O += P V  (K=16 MFMA; conflict-free b64 V reads)
            const int vc = (((ct * 2 + q2) ^ swz)) * 8 + vhalf;
#if __has_builtin(__builtin_amdgcn_mfma_f32_16x16x16bf16_1k)
            #pragma unroll
            for (int dct = 0; dct < 8; ++dct) {
                short4v bfr = *(const short4v*)&Vs[(dct * 16 + l16) * 128 + vc];
                oacc[0][dct] = __builtin_amdgcn_mfma_f32_16x16x16bf16_1k(pp[0], bfr, oacc[0][dct], 0, 0, 0);
                oacc[1][dct] = __builtin_amdgcn_mfma_f32_16x16x16bf16_1k(pp[1], bfr, oacc[1][dct], 0, 0, 0);
            }
#else
            #pragma unroll
            for (int dct = 0; dct < 8; ++dct) {
                union { short8 s8; short4v s4[2]; } b;
                b.s4[0] = *(const short4v*)&Vs[(dct * 16 + l16) * 128 + vc];
                b.s4[1] = short4v{0, 0, 0, 0};
                #pragma unroll
                for (int rt = 0; rt < 2; ++rt) {
                    union { short8 s8; short4v s4[2]; } a;
                    a.s4[0] = pp[rt];
                    a.s4[1] = short4v{0, 0, 0, 0};
                    oacc[rt][dct] = __builtin_amdgcn_mfma_f32_16x16x32_bf16(a.s8, b.s8, oacc[rt][dct], 0, 0, 0);
                }
            }
#endif
        }
        __syncthreads();   // bar2: Ks/Vs reads done before next staging
    }

    // ---- epilogue: reduce l across quads, redistribute, normalize, store
    float lred[2];
    #pragma unroll
    for (int rt = 0; rt < 2; ++rt) {
        float l = l_s[rt];
        l += __shfl_xor(l, 16, 64);
        l += __shfl_xor(l, 32, 64);
        lred[rt] = l;                 // valid for t = l16 (+rt*16) in all quads
    }
    #pragma unroll
    for (int rt = 0; rt < 2; ++rt)
        #pragma unroll
        for (int r = 0; r < 4; ++r) {
            float l = __shfl(lred[rt], quad * 4 + r, 64);
            float linv = 1.0f / l;
            int rowg = t0 + wave * 32 + rt * 16 + quad * 4 + r;
            #pragma unroll
            for (int dct = 0; dct < 8; ++dct)
                qkv[(size_t)rowg * QKV_W + h * HD + dct * 16 + l16] = f2bf(oacc[rt][dct][r] * linv);
        }
}

extern "C" void kernel_launch(void* const* d_in, const int* in_sizes, int n_in,
                              void* d_out, int out_size, void* d_ws, size_t ws_size,
                              hipStream_t stream) {
    const int*   positions = (const int*)d_in[0];
    const float* hidden    = (const float*)d_in[1];
    const float* w_qkv     = (const float*)d_in[2];
    const float* w_o       = (const float*)d_in[3];
    const float* q_norm_w  = (const float*)d_in[4];
    const float* k_norm_w  = (const float*)d_in[5];
    float* out = (float*)d_out;

    unsigned short* qkvb   = (unsigned short*)d_ws;
    unsigned short* h_bf   = (unsigned short*)((char*)d_ws + ((size_t)32 << 20));
    unsigned short* Kp     = (unsigned short*)((char*)d_ws + ((size_t)32 << 20));
    unsigned short* Vp     = (unsigned short*)((char*)d_ws + ((size_t)40 << 20));
    unsigned short* wqkv_t = (unsigned short*)((char*)d_ws + ((size_t)48 << 20));
    unsigned short* wo_t   = (unsigned short*)((char*)d_ws + ((size_t)48 << 20));

    cvt_bf16<<<(T_TOK * H_DIM) / (256 * 8), 256, 0, stream>>>(hidden, h_bf);
    cvt_transpose<<<dim3(QKV_W / 64, H_DIM / 64), 256, 0, stream>>>(w_qkv, wqkv_t, H_DIM, QKV_W);
    // QKV: M=4096, N=4096, K=2048 -> grid 16*16 = 256 blocks, 1 block/CU
    gemm8p<true><<<dim3(256), 512, 0, stream>>>(
        h_bf, H_DIM, wqkv_t, H_DIM, qkvb, QKV_W, H_DIM, QKV_W / 256);
    rms_rope_bf16<<<T_TOK, 256, 0, stream>>>(qkvb, positions, q_norm_w, k_norm_w);
    kv_pack<<<dim3(T_TOK / 128, NKV), 256, 0, stream>>>(qkvb, Kp, Vp);
    cvt_transpose<<<dim3(H_DIM / 64, QS / 64), 256, 0, stream>>>(w_o, wo_t, QS, H_DIM);
    attn_mfma<<<512, 256, 0, stream>>>(qkvb, Kp, Vp);
    // WO: M=4096, N=2048, K=2048 -> 128^2 tiles, 512 blocks (2/CU, all CUs busy)
    gemm_bt<false><<<dim3(H_DIM / 128, T_TOK / 128), 256, 0, stream>>>(
        qkvb, QKV_W, wo_t, QS, out, H_DIM, QS);
}

// Round 7
// 344.829 us; speedup vs baseline: 1.1228x; 1.0719x over previous
//
#include <hip/hip_runtime.h>
#include <hip/hip_bf16.h>
#include <math.h>

#define T_TOK 4096
#define H_DIM 2048
#define NH 16
#define NKV 8
#define HD 128
#define QS (NH * HD)        // 2048
#define KVS (NKV * HD)      // 1024
#define QKV_W (QS + 2*KVS)  // 4096
// SCALE * log2(e): Q pre-scaled so softmax runs in exp2 domain
#define QSCALE (0.08838834764831845f * 1.4426950408889634f)
#define EPS 1e-6f

typedef short short8 __attribute__((ext_vector_type(8)));
typedef short short4v __attribute__((ext_vector_type(4)));
typedef float floatx4 __attribute__((ext_vector_type(4)));

#if __has_builtin(__builtin_amdgcn_exp2f)
#define EXP2(x) __builtin_amdgcn_exp2f(x)
#else
#define EXP2(x) exp2f(x)
#endif

__device__ __forceinline__ unsigned short f2bf(float f) {
    unsigned int u = __float_as_uint(f);
    unsigned int r = (u + 0x7FFFu + ((u >> 16) & 1u)) >> 16;   // RNE
    return (unsigned short)r;
}
__device__ __forceinline__ float bf2f(unsigned short u) {
    unsigned int v = ((unsigned int)u) << 16;
    return __uint_as_float(v);
}
// packed f32x2 -> bf16x2
__device__ __forceinline__ unsigned int pk2(float a, float b) {
    union { __hip_bfloat162 h; unsigned int u; } c;
    c.h = __float22bfloat162_rn(make_float2(a, b));
    return c.u;
}

// async global->LDS 16B: LDS dest is wave-uniform base + lane*16
__device__ __forceinline__ void gload_lds16(const unsigned short* g, unsigned short* l) {
    __builtin_amdgcn_global_load_lds(
        (const __attribute__((address_space(1))) unsigned int*)(const void*)g,
        (__attribute__((address_space(3))) unsigned int*)(void*)l, 16, 0, 0);
}

// ---------------- f32 -> bf16 flat convert ---------------------------------
__global__ __launch_bounds__(256) void cvt_bf16(const float* __restrict__ in,
                                                unsigned short* __restrict__ out) {
    int idx = (blockIdx.x * 256 + threadIdx.x) * 8;
    float4 v0 = *(const float4*)&in[idx];
    float4 v1 = *(const float4*)&in[idx + 4];
    short8 t;
    t[0] = (short)f2bf(v0.x); t[1] = (short)f2bf(v0.y);
    t[2] = (short)f2bf(v0.z); t[3] = (short)f2bf(v0.w);
    t[4] = (short)f2bf(v1.x); t[5] = (short)f2bf(v1.y);
    t[6] = (short)f2bf(v1.z); t[7] = (short)f2bf(v1.w);
    *(short8*)&out[idx] = t;
}

// ------------- f32 [K][N] -> bf16 [N][K] transpose+convert -----------------
__global__ __launch_bounds__(256) void cvt_transpose(const float* __restrict__ in,
                                                     unsigned short* __restrict__ out,
                                                     int K, int N) {
    __shared__ __align__(16) unsigned short t[64][72];
    const int tid = threadIdx.x;
    const int n0 = blockIdx.x * 64, k0 = blockIdx.y * 64;
    const int r = tid >> 4, c4 = (tid & 15) * 4;
    #pragma unroll
    for (int i = 0; i < 4; ++i) {
        int kk = r + 16 * i;
        float4 v = *(const float4*)&in[(size_t)(k0 + kk) * N + n0 + c4];
        t[c4 + 0][kk] = f2bf(v.x); t[c4 + 1][kk] = f2bf(v.y);
        t[c4 + 2][kk] = f2bf(v.z); t[c4 + 3][kk] = f2bf(v.w);
    }
    __syncthreads();
    const int n = tid >> 2, c8 = (tid & 3) * 16;
    short8 a = *(const short8*)&t[n][c8];
    short8 b = *(const short8*)&t[n][c8 + 8];
    *(short8*)&out[(size_t)(n0 + n) * K + k0 + c8] = a;
    *(short8*)&out[(size_t)(n0 + n) * K + k0 + c8 + 8] = b;
}

// ====== 256xBN pipelined bf16 GEMM: C[M,N] = A[M,K] @ Bt[N,K]^T ============
// BK=64, 2 whole-K-tile LDS buffers.  Per K-tile: ONE vmcnt(0) (fully covered
// by the previous tile's compute) + ONE barrier, then stage the entire next
// tile into the other buffer, then 4 unbarriered ds_read+MFMA phases the
// compiler is free to software-pipeline.  setprio around compute (T5), XOR
// chunk swizzle both-sides (pre-swizzled global src + swizzled ds_read),
// XCD-chunked block swizzle (grid % 8 == 0).
// 8 waves = 2(M) x 4(N); per-wave output 128 x BN/4.
template<bool C_BF16, int BN>
__global__ __launch_bounds__(512, 2) void gemm8p(const unsigned short* __restrict__ A, int lda,
                                                 const unsigned short* __restrict__ Bt, int ldb,
                                                 void* __restrict__ Cptr, int ldc, int K, int nbx) {
    constexpr int LDSTILE = 16384 + BN * 64;      // ushorts: A 256x64 + B BNx64
    constexpr int NFRAG = BN / 64;                // B frags per wave per kk
    __shared__ __align__(16) unsigned short lds[2 * LDSTILE];
    const int tid  = threadIdx.x;
    const int wave = tid >> 6, lane = tid & 63;
    const int quad = lane >> 4, l16 = lane & 15;
    const int wm = wave >> 2, wn = wave & 3;

    // XCD-chunked bijective swizzle (gridDim.x % 8 == 0)
    const int cpx = gridDim.x >> 3;
    const int swzb = (blockIdx.x & 7) * cpx + (blockIdx.x >> 3);
    const int by = swzb / nbx, bx = swzb % nbx;
    const int bm = by * 256, bn = bx * BN;

    // staging invariants: per 128-row half-panel, 1024 chunks, 2 per thread
    const int ch0 = wave * 64 + lane, ch1 = 512 + ch0;
    const int r0 = ch0 >> 3, gc0 = ((ch0 & 7) ^ (r0 & 7)) * 8;
    const int r1 = ch1 >> 3, gc1 = ((ch1 & 7) ^ (r1 & 7)) * 8;
    const unsigned du0 = (unsigned)(wave * 64) * 8;
    const unsigned du1 = (unsigned)(512 + wave * 64) * 8;

    auto stageP = [&](const unsigned short* P, int bp, int ld,
                      unsigned short* dstbase, int rhalf, int kt) {
        unsigned short* dst = dstbase + rhalf * 64;
        gload_lds16(P + (size_t)(bp + rhalf + r0) * ld + kt * 64 + gc0, dst + du0);
        gload_lds16(P + (size_t)(bp + rhalf + r1) * ld + kt * 64 + gc1, dst + du1);
    };
    auto stage = [&](int kt, int buf) {                 // whole tile: A + B
        unsigned short* ab = &lds[buf * LDSTILE];
        unsigned short* bb = ab + 16384;
        stageP(A, bm, lda, ab, 0, kt);
        stageP(A, bm, lda, ab, 128, kt);
        stageP(Bt, bn, ldb, bb, 0, kt);
        if (BN == 256) stageP(Bt, bn, ldb, bb, 128, kt);
    };

    floatx4 acc[8][NFRAG] = {};
    const int arowb = wm * 128 + l16;
    const int browb = wn * (BN / 4) + l16;
    const int sw = l16 & 7;

    auto compute = [&](int buf) {
        const unsigned short* ab = &lds[buf * LDSTILE];
        const unsigned short* bb = ab + 16384;
        __builtin_amdgcn_s_setprio(1);
        #pragma unroll
        for (int kk = 0; kk < 2; ++kk) {
            const int sl = ((kk * 4 + quad) ^ sw) * 8;
            short8 bfr[NFRAG];
            #pragma unroll
            for (int ni = 0; ni < NFRAG; ++ni)
                bfr[ni] = *(const short8*)&bb[(browb + ni * 16) * 64 + sl];
            #pragma unroll
            for (int mh = 0; mh < 2; ++mh) {
                short8 afr[4];
                #pragma unroll
                for (int mi = 0; mi < 4; ++mi)
                    afr[mi] = *(const short8*)&ab[(arowb + (mh * 4 + mi) * 16) * 64 + sl];
                #pragma unroll
                for (int mi = 0; mi < 4; ++mi)
                    #pragma unroll
                    for (int ni = 0; ni < NFRAG; ++ni)
                        acc[mh * 4 + mi][ni] =
                            __builtin_amdgcn_mfma_f32_16x16x32_bf16(afr[mi], bfr[ni], acc[mh * 4 + mi][ni], 0, 0, 0);
            }
        }
        __builtin_amdgcn_s_setprio(0);
    };

    const int NT = K >> 6;                        // K-tiles of 64
    stage(0, 0);
    int cur = 0;
    for (int kt = 0; kt < NT; ++kt) {
        asm volatile("s_waitcnt vmcnt(0)" ::: "memory");  // my tile-kt loads landed
                                                          // (issued a full tile of compute ago)
        __builtin_amdgcn_s_barrier();                     // all waves: tile-kt visible,
                                                          // tile-(kt-1) reads complete
        if (kt + 1 < NT) stage(kt + 1, cur ^ 1);          // other buf is free now
        compute(cur);                                     // unbarriered; compiler pipelines
        cur ^= 1;
    }

    // ---- epilogue: C[row, col]
    #pragma unroll
    for (int mi = 0; mi < 8; ++mi)
        #pragma unroll
        for (int ni = 0; ni < NFRAG; ++ni)
            #pragma unroll
            for (int r = 0; r < 4; ++r) {
                int row = bm + wm * 128 + mi * 16 + quad * 4 + r;
                int col = bn + wn * (BN / 4) + ni * 16 + l16;
                if (C_BF16)
                    ((unsigned short*)Cptr)[(size_t)row * ldc + col] = f2bf(acc[mi][ni][r]);
                else
                    ((float*)Cptr)[(size_t)row * ldc + col] = acc[mi][ni][r];
            }
}

// ============ per-head RMSNorm + RoPE; q additionally scaled by QSCALE =====
__global__ __launch_bounds__(256) void rms_rope_bf16(unsigned short* __restrict__ qkv,
                                                     const int* __restrict__ positions,
                                                     const float* __restrict__ qw,
                                                     const float* __restrict__ kw) {
    const int t = blockIdx.x;
    const int wave = threadIdx.x >> 6;
    const int lane = threadIdx.x & 63;
    const float pos = (float)positions[t];
    unsigned short* row = qkv + (size_t)t * QKV_W;
    // 1e6^(-lane/64) = exp2(-lane * log2(1e6)/64)
    const float inv_freq = exp2f(-(float)lane * (19.931568569324174f / 64.0f));
    float sv, cv;
    sincosf(pos * inv_freq, &sv, &cv);
    for (int h = wave; h < NH + NKV; h += 4) {
        unsigned short* x = row + h * HD;
        const float* w = (h < NH) ? qw : kw;
        const float hs = (h < NH) ? QSCALE : 1.0f;
        float x1 = bf2f(x[lane]);
        float x2 = bf2f(x[lane + 64]);
        float ss = x1 * x1 + x2 * x2;
        #pragma unroll
        for (int off = 32; off > 0; off >>= 1) ss += __shfl_xor(ss, off, 64);
        float r = rsqrtf(ss * (1.0f / 128.0f) + EPS) * hs;
        float n1 = x1 * r * w[lane];
        float n2 = x2 * r * w[lane + 64];
        x[lane]      = f2bf(n1 * cv - n2 * sv);
        x[lane + 64] = f2bf(n2 * cv + n1 * sv);
    }
}

// ====== KV pre-pack: per kvh, per 128-token tile, contiguous 32 KB tiles ===
// Kp tile: chunk (s, c) -> slot s*16 + (c ^ (s&7))           [s=token, c=dim/8]
// Vp tile: V^T chunk (d, cs) -> slot d*16 + (cs ^ (d&7)); within-chunk halves
//          (2x 4 tokens) swapped iff (d>>3)&1  -> conflict-free b64 reads
__global__ __launch_bounds__(256) void kv_pack(const unsigned short* __restrict__ qkv,
                                               unsigned short* __restrict__ Kp,
                                               unsigned short* __restrict__ Vp) {
    const int tile = blockIdx.x, kvh = blockIdx.y, tid = threadIdx.x;
    const int t0 = tile * 128;
    const size_t tb = (size_t)(kvh * 32 + tile) * 16384;
    // ---- K: swizzle chunks within each row
    #pragma unroll
    for (int i = 0; i < 8; ++i) {
        int cid = i * 256 + tid;
        int s = cid >> 4, c = cid & 15;
        short8 v = *(const short8*)&qkv[(size_t)(t0 + s) * QKV_W + QS + kvh * HD + c * 8];
        *(short8*)&Kp[tb + (s * 16 + (c ^ (s & 7))) * 8] = v;
    }
    // ---- V: transpose via LDS
    __shared__ __align__(16) unsigned short Lt[128 * 136];
    #pragma unroll
    for (int i = 0; i < 8; ++i) {
        int cid = i * 256 + tid;
        int s = cid >> 4, c = cid & 15;
        short8 v = *(const short8*)&qkv[(size_t)(t0 + s) * QKV_W + QS + KVS + kvh * HD + c * 8];
        // rotated element order: lanes with different c hit different banks
        #pragma unroll
        for (int e = 0; e < 8; ++e) {
            int ee = (e + c) & 7;
            Lt[(c * 8 + ee) * 136 + s] = (unsigned short)v[ee];
        }
    }
    __syncthreads();
    #pragma unroll
    for (int i = 0; i < 8; ++i) {
        int cid = i * 256 + tid;
        int d = cid >> 4, cs = cid & 15;
        short8 v = *(const short8*)&Lt[d * 136 + cs * 8];
        short8 w;
        if ((d >> 3) & 1) {
            #pragma unroll
            for (int e = 0; e < 8; ++e) w[e] = v[e ^ 4];   // swap 4-token halves
        } else w = v;
        *(short8*)&Vp[tb + (d * 16 + (cs ^ (d & 7))) * 8] = w;
    }
}

// ================= MFMA causal GQA flash attention =========================
// Transposed-S scheme (S^T = K·Q^T); 128 q-rows/block, 128 kv/step.
// ct-interleaved: per 16-col block do QK^T -> exp2/pack -> PV immediately.
// LDS Ks+Vs = 64 KB -> 2 blocks/CU. Balanced pairing: blocks (c, c+256)
// get qt and 31-qt.  (round-4 version: 114.6 us, MfmaUtil 37%)
__global__ __launch_bounds__(256, 2) void attn_mfma(unsigned short* __restrict__ qkv,
                                                    const unsigned short* __restrict__ Kp,
                                                    const unsigned short* __restrict__ Vp) {
    __shared__ __align__(16) unsigned short Ks[128 * 128];
    __shared__ __align__(16) unsigned short Vs[128 * 128];
    const int bx = blockIdx.x;
    const int h = bx & 15, kvh = h >> 1;            // XCD = bx%8 tracks h%8
    const int g = bx >> 4;                          // 0..31
    const int qt = (g < 16) ? (31 - g) : (g - 16);  // pair sums = 31
    const int tid = threadIdx.x;
    const int wave = tid >> 6, lane = tid & 63;
    const int quad = lane >> 4, l16 = lane & 15;
    const int t0 = qt * 128;
    const int wrow0 = t0 + wave * 32;
    const int swz = l16 & 7;
    const int hsel = (l16 >> 3) & 1;                // V half-swap selector
    const int vhalf = ((quad & 1) ^ hsel) * 4;
    const int q2 = quad >> 1;

    // Q fragments (pre-scaled by QSCALE); B-operand of K·Q^T
    short8 qf[2][4];
    #pragma unroll
    for (int rt = 0; rt < 2; ++rt)
        #pragma unroll
        for (int ks = 0; ks < 4; ++ks) {
            int rowg = t0 + wave * 32 + rt * 16 + l16;
            qf[rt][ks] = *(const short8*)&qkv[(size_t)rowg * QKV_W + h * HD + ks * 32 + quad * 8];
        }

    float l_s[2] = {};
    floatx4 oacc[2][8] = {};

    for (int st = 0; st <= qt; ++st) {
        const int s0 = st * 128;
        const unsigned short* kb = Kp + (size_t)(kvh * 32 + st) * 16384;
        const unsigned short* vb = Vp + (size_t)(kvh * 32 + st) * 16384;
        #pragma unroll
        for (int i = 0; i < 8; ++i) {
            int ch = i * 256 + tid;
            gload_lds16(kb + (size_t)ch * 8, Ks + (i * 256 + wave * 64) * 8);
        }
        #pragma unroll
        for (int i = 0; i < 8; ++i) {
            int ch = i * 256 + tid;
            gload_lds16(vb + (size_t)ch * 8, Vs + (i * 256 + wave * 64) * 8);
        }
        __syncthreads();   // bar1: staging visible

        const bool diag = (st == qt);
        #pragma unroll
        for (int ct = 0; ct < 8; ++ct) {
            const int smin = s0 + ct * 16;
            if (diag && smin > wrow0 + 31) continue;   // wave-uniform causal skip
            // ---- S^T block: C[s=quad*4+r][t=l16 (+16rt)]
            floatx4 sacc[2] = {};
            #pragma unroll
            for (int ks = 0; ks < 4; ++ks) {
                short8 kfr = *(const short8*)&Ks[(ct * 16 + l16) * 128 + ((ks * 4 + quad) ^ swz) * 8];
                sacc[0] = __builtin_amdgcn_mfma_f32_16x16x32_bf16(kfr, qf[0][ks], sacc[0], 0, 0, 0);
                sacc[1] = __builtin_amdgcn_mfma_f32_16x16x32_bf16(kfr, qf[1][ks], sacc[1], 0, 0, 0);
            }
            // ---- exp2 + pack into PV A-fragments
            short4v pp[2];
            #pragma unroll
            for (int rt = 0; rt < 2; ++rt) {
                const int tg = wrow0 + rt * 16 + l16;
                float p[4];
                float lsum = 0.0f;
                #pragma unroll
                for (int r = 0; r < 4; ++r) {
                    float s = sacc[rt][r];
                    if (diag && (smin + quad * 4 + r > tg)) s = -1e30f;
                    p[r] = EXP2(s);
                    lsum += p[r];
                }
                l_s[rt] += lsum;
                union { short4v s4; unsigned int u[2]; } pk;
                pk.u[0] = pk2(p[0], p[1]);
                pk.u[1] = pk2(p[2], p[3]);
                pp[rt] = pk.s4;
            }
            // ---- O += P V  (K=16 MFMA; conflict-free b64 V reads)
            const int vc = (((ct * 2 + q2) ^ swz)) * 8 + vhalf;
#if __has_builtin(__builtin_amdgcn_mfma_f32_16x16x16bf16_1k)
            #pragma unroll
            for (int dct = 0; dct < 8; ++dct) {
                short4v bfr = *(const short4v*)&Vs[(dct * 16 + l16) * 128 + vc];
                oacc[0][dct] = __builtin_amdgcn_mfma_f32_16x16x16bf16_1k(pp[0], bfr, oacc[0][dct], 0, 0, 0);
                oacc[1][dct] = __builtin_amdgcn_mfma_f32_16x16x16bf16_1k(pp[1], bfr, oacc[1][dct], 0, 0, 0);
            }
#else
            #pragma unroll
            for (int dct = 0; dct < 8; ++dct) {
                union { short8 s8; short4v s4[2]; } b;
                b.s4[0] = *(const short4v*)&Vs[(dct * 16 + l16) * 128 + vc];
                b.s4[1] = short4v{0, 0, 0, 0};
                #pragma unroll
                for (int rt = 0; rt < 2; ++rt) {
                    union { short8 s8; short4v s4[2]; } a;
                    a.s4[0] = pp[rt];
                    a.s4[1] = short4v{0, 0, 0, 0};
                    oacc[rt][dct] = __builtin_amdgcn_mfma_f32_16x16x32_bf16(a.s8, b.s8, oacc[rt][dct], 0, 0, 0);
                }
            }
#endif
        }
        __syncthreads();   // bar2: Ks/Vs reads done before next staging
    }

    // ---- epilogue: reduce l across quads, redistribute, normalize, store
    float lred[2];
    #pragma unroll
    for (int rt = 0; rt < 2; ++rt) {
        float l = l_s[rt];
        l += __shfl_xor(l, 16, 64);
        l += __shfl_xor(l, 32, 64);
        lred[rt] = l;                 // valid for t = l16 (+rt*16) in all quads
    }
    #pragma unroll
    for (int rt = 0; rt < 2; ++rt)
        #pragma unroll
        for (int r = 0; r < 4; ++r) {
            float l = __shfl(lred[rt], quad * 4 + r, 64);
            float linv = 1.0f / l;
            int rowg = t0 + wave * 32 + rt * 16 + quad * 4 + r;
            #pragma unroll
            for (int dct = 0; dct < 8; ++dct)
                qkv[(size_t)rowg * QKV_W + h * HD + dct * 16 + l16] = f2bf(oacc[rt][dct][r] * linv);
        }
}

extern "C" void kernel_launch(void* const* d_in, const int* in_sizes, int n_in,
                              void* d_out, int out_size, void* d_ws, size_t ws_size,
                              hipStream_t stream) {
    const int*   positions = (const int*)d_in[0];
    const float* hidden    = (const float*)d_in[1];
    const float* w_qkv     = (const float*)d_in[2];
    const float* w_o       = (const float*)d_in[3];
    const float* q_norm_w  = (const float*)d_in[4];
    const float* k_norm_w  = (const float*)d_in[5];
    float* out = (float*)d_out;

    unsigned short* qkvb   = (unsigned short*)d_ws;
    unsigned short* h_bf   = (unsigned short*)((char*)d_ws + ((size_t)32 << 20));
    unsigned short* Kp     = (unsigned short*)((char*)d_ws + ((size_t)32 << 20));
    unsigned short* Vp     = (unsigned short*)((char*)d_ws + ((size_t)40 << 20));
    unsigned short* wqkv_t = (unsigned short*)((char*)d_ws + ((size_t)48 << 20));
    unsigned short* wo_t   = (unsigned short*)((char*)d_ws + ((size_t)48 << 20));

    cvt_bf16<<<(T_TOK * H_DIM) / (256 * 8), 256, 0, stream>>>(hidden, h_bf);
    cvt_transpose<<<dim3(QKV_W / 64, H_DIM / 64), 256, 0, stream>>>(w_qkv, wqkv_t, H_DIM, QKV_W);
    // QKV: M=4096, N=4096, K=2048, BN=256 -> grid 16*16 = 256 blocks, 1/CU
    gemm8p<true, 256><<<dim3(256), 512, 0, stream>>>(
        h_bf, H_DIM, wqkv_t, H_DIM, qkvb, QKV_W, H_DIM, QKV_W / 256);
    rms_rope_bf16<<<T_TOK, 256, 0, stream>>>(qkvb, positions, q_norm_w, k_norm_w);
    kv_pack<<<dim3(T_TOK / 128, NKV), 256, 0, stream>>>(qkvb, Kp, Vp);
    cvt_transpose<<<dim3(H_DIM / 64, QS / 64), 256, 0, stream>>>(w_o, wo_t, QS, H_DIM);
    attn_mfma<<<512, 256, 0, stream>>>(qkvb, Kp, Vp);
    // WO: M=4096, N=2048, K=2048, BN=128 -> grid 16*16 = 256 blocks, 1/CU
    gemm8p<false, 128><<<dim3(256), 512, 0, stream>>>(
        qkvb, QKV_W, wo_t, QS, out, H_DIM, QS, H_DIM / 128);
}